// Round 6
// baseline (367.238 us; speedup 1.0000x reference)
//
#include <hip/hip_runtime.h>
#include <hip/hip_fp16.h>

#define NN 100000
#define NE 2500000
#define RANGE 256
#define NBUCK 391                       // ceil(NN/256)
#define CHUNK 8192
#define NBLK_A ((NE + CHUNK - 1) / CHUNK)   // 306

__device__ __forceinline__ float relu_(float x){ return fmaxf(x, 0.f); }

// h16[n,0:32] = relu(nf[n,0:2] @ W_in + b_in)  (fp16 master)
__global__ __launch_bounds__(256) void k_node_embed16(
    const float* __restrict__ nf, const float* __restrict__ Win,
    const float* __restrict__ bin, __half* __restrict__ h16)
{
  int n = blockIdx.x * 256 + threadIdx.x;
  if (n >= NN) return;
  float f0 = nf[2*n], f1 = nf[2*n+1];
  const float4* W0 = (const float4*)Win;
  const float4* W1 = (const float4*)(Win + 32);
  const float4* B  = (const float4*)bin;
  __half2* g2 = (__half2*)(h16 + (size_t)n * 32);
#pragma unroll
  for (int j = 0; j < 8; ++j) {
    float4 w0 = W0[j], w1 = W1[j], b = B[j], r;
    r.x = relu_(fmaf(f0, w0.x, fmaf(f1, w1.x, b.x)));
    r.y = relu_(fmaf(f0, w0.y, fmaf(f1, w1.y, b.y)));
    r.z = relu_(fmaf(f0, w0.z, fmaf(f1, w1.z, b.z)));
    r.w = relu_(fmaf(f0, w0.w, fmaf(f1, w1.w, b.w)));
    g2[2*j]   = __floats2half2_rn(r.x, r.y);
    g2[2*j+1] = __floats2half2_rn(r.z, r.w);
  }
}

// ---- CSR build (counting sort by row, carries orig edge id) ----

__global__ __launch_bounds__(512) void k_histA(const int* __restrict__ row,
                                               int* __restrict__ btot,
                                               int* __restrict__ blockhist)
{
  __shared__ int hist[NBUCK];
  int t = threadIdx.x;
  for (int i = t; i < NBUCK; i += 512) hist[i] = 0;
  __syncthreads();
  int e0 = blockIdx.x * CHUNK + t;
#pragma unroll
  for (int k = 0; k < CHUNK / 512; ++k) {
    int e = e0 + k * 512;
    if (e < NE) atomicAdd(&hist[row[e] >> 8], 1);
  }
  __syncthreads();
  for (int i = t; i < NBUCK; i += 512) {
    int c = hist[i];
    blockhist[(size_t)i * NBLK_A + blockIdx.x] = c;
    if (c) atomicAdd(&btot[i], c);
  }
}

__global__ __launch_bounds__(512) void k_scanA(const int* __restrict__ btot,
                                               int* __restrict__ bbase)
{
  __shared__ int s[512];
  int t = threadIdx.x;
  int my = (t < NBUCK) ? btot[t] : 0;
  s[t] = my;
  __syncthreads();
  for (int off = 1; off < 512; off <<= 1) {
    int v = (t >= off) ? s[t - off] : 0;
    __syncthreads();
    s[t] += v;
    __syncthreads();
  }
  if (t < NBUCK) bbase[t] = s[t] - my;
  if (t == 0) bbase[NBUCK] = NE;
}

__global__ __launch_bounds__(512) void k_colscan(int* __restrict__ blockhist,
                                                 const int* __restrict__ bbase)
{
  __shared__ int s[512];
  int i = blockIdx.x, t = threadIdx.x;
  int* rowp = blockhist + (size_t)i * NBLK_A;
  int my = (t < NBLK_A) ? rowp[t] : 0;
  s[t] = my;
  __syncthreads();
  for (int off = 1; off < 512; off <<= 1) {
    int v = (t >= off) ? s[t - off] : 0;
    __syncthreads();
    s[t] += v;
    __syncthreads();
  }
  if (t < NBLK_A) rowp[t] = bbase[i] + s[t] - my;
}

__global__ __launch_bounds__(512) void k_partition2(
    const int* __restrict__ row, const int* __restrict__ col,
    const int* __restrict__ blockhist, uint2* __restrict__ keys)
{
  __shared__ int cur[NBUCK];
  __shared__ int base[NBUCK];
  int t = threadIdx.x, b = blockIdx.x;
  for (int i = t; i < NBUCK; i += 512) {
    base[i] = blockhist[(size_t)i * NBLK_A + b];
    cur[i] = 0;
  }
  __syncthreads();
  int e0 = b * CHUNK + t;
#pragma unroll
  for (int k = 0; k < CHUNK / 512; ++k) {
    int e = e0 + k * 512;
    if (e < NE) {
      int r = row[e];
      int bi = r >> 8;
      int idx = atomicAdd(&cur[bi], 1);
      uint2 kk;
      kk.x = ((unsigned)col[e] << 8) | (unsigned)(r & 255);
      kk.y = (unsigned)e;
      keys[base[bi] + idx] = kk;
    }
  }
}

__global__ __launch_bounds__(512) void k_passB2(
    const int* __restrict__ bbase, const uint2* __restrict__ keys,
    int* __restrict__ ecol, int* __restrict__ eorig, int* __restrict__ rowptr)
{
  __shared__ int hist[RANGE];
  __shared__ int sc[RANGE];
  int t = threadIdx.x, b = blockIdx.x;
  int s0 = bbase[b], e0 = bbase[b + 1];
  if (t < RANGE) hist[t] = 0;
  __syncthreads();
  for (int i = s0 + t; i < e0; i += 512)
    atomicAdd(&hist[keys[i].x & 255u], 1);
  __syncthreads();
  int my = (t < RANGE) ? hist[t] : 0;
  if (t < RANGE) sc[t] = my;
  __syncthreads();
  for (int off = 1; off < RANGE; off <<= 1) {
    int v = 0;
    if (t < RANGE && t >= off) v = sc[t - off];
    __syncthreads();
    if (t < RANGE) sc[t] += v;
    __syncthreads();
  }
  if (t < RANGE) {
    int ex = sc[t] - my;
    int n = b * RANGE + t;
    if (n <= NN) rowptr[n] = s0 + ex;
    hist[t] = ex;
  }
  __syncthreads();
  for (int i = s0 + t; i < e0; i += 512) {
    uint2 key = keys[i];
    int rl = (int)(key.x & 255u);
    int idx = atomicAdd(&hist[rl], 1);
    ecol[s0 + idx]  = (int)(key.x >> 8);
    eorig[s0 + idx] = (int)key.y;
  }
}

// ---- fused: agg = mean gather(h16in[ecol]); x = [h16in[n], agg];
//      hout = relu(x @ W + b)  -> h16out          (64 nodes x 4 lanes / block)
__global__ __launch_bounds__(256) void k_agg_update(
    const int* __restrict__ rowptr, const int* __restrict__ ecol,
    const __half* __restrict__ h16in, const float* __restrict__ W,
    const float* __restrict__ b, __half* __restrict__ h16out)
{
  __shared__ float Ws[2048];
  __shared__ float bs[32];
  __shared__ float xs[64][65];
  int t = threadIdx.x;
  for (int i = t; i < 2048; i += 256) Ws[i] = W[i];
  if (t < 32) bs[t] = b[t];
  int q = t & 3, ln = t >> 2;
  int n = blockIdx.x * 64 + ln;
  bool act = (n < NN);
  const uint4* hv = (const uint4*)h16in;

  float acc[8];
#pragma unroll
  for (int j = 0; j < 8; ++j) acc[j] = 0.f;
  if (act) {
    int s = rowptr[n], e = rowptr[n + 1];
    for (int i = s; i < e; ++i) {
      int c = ecol[i];
      uint4 x = hv[c * 4 + q];
      const __half2* hp = (const __half2*)&x;
#pragma unroll
      for (int k = 0; k < 4; ++k) {
        float2 f = __half22float2(hp[k]);
        acc[2*k] += f.x; acc[2*k+1] += f.y;
      }
    }
    float dinv = 1.0f / fmaxf((float)(e - s), 1.0f);
    uint4 hx = hv[n * 4 + q];
    const __half2* hp = (const __half2*)&hx;
#pragma unroll
    for (int k = 0; k < 4; ++k) {
      float2 f = __half22float2(hp[k]);
      xs[ln][q*8 + 2*k]     = f.x;
      xs[ln][q*8 + 2*k + 1] = f.y;
      xs[ln][32 + q*8 + 2*k]     = acc[2*k] * dinv;
      xs[ln][32 + q*8 + 2*k + 1] = acc[2*k+1] * dinv;
    }
  }
  __syncthreads();
  if (!act) return;
  float o[8];
#pragma unroll
  for (int j = 0; j < 8; ++j) o[j] = bs[q*8 + j];
  for (int k = 0; k < 64; ++k) {
    float xk = xs[ln][k];
    const float* wr = Ws + k * 32 + q * 8;
#pragma unroll
    for (int j = 0; j < 8; ++j) o[j] = fmaf(xk, wr[j], o[j]);
  }
  uint4 pk;
  __half2* pp = (__half2*)&pk;
#pragma unroll
  for (int k = 0; k < 4; ++k)
    pp[k] = __floats2half2_rn(relu_(o[2*k]), relu_(o[2*k+1]));
  ((uint4*)h16out)[n * 4 + q] = pk;
}

// ---- fused layer-2 + edge projection: h2 = relu(x@W+b);
//      u = h2@We1[0:32]+be1, v = h2@We1[32:64]  (fp16 out)
__global__ __launch_bounds__(256) void k_agg_update2_uv(
    const int* __restrict__ rowptr, const int* __restrict__ ecol,
    const __half* __restrict__ h16in, const float* __restrict__ W,
    const float* __restrict__ b, const float* __restrict__ We1,
    const float* __restrict__ be1, __half* __restrict__ u,
    __half* __restrict__ v)
{
  __shared__ float Ws[2048];
  __shared__ float Es[2048];
  __shared__ float bs[32];
  __shared__ float bes[32];
  __shared__ float xs[64][65];
  int t = threadIdx.x;
  for (int i = t; i < 2048; i += 256) { Ws[i] = W[i]; Es[i] = We1[i]; }
  if (t < 32) { bs[t] = b[t]; bes[t] = be1[t]; }
  int q = t & 3, ln = t >> 2;
  int n = blockIdx.x * 64 + ln;
  bool act = (n < NN);
  const uint4* hv = (const uint4*)h16in;

  float acc[8];
#pragma unroll
  for (int j = 0; j < 8; ++j) acc[j] = 0.f;
  if (act) {
    int s = rowptr[n], e = rowptr[n + 1];
    for (int i = s; i < e; ++i) {
      int c = ecol[i];
      uint4 x = hv[c * 4 + q];
      const __half2* hp = (const __half2*)&x;
#pragma unroll
      for (int k = 0; k < 4; ++k) {
        float2 f = __half22float2(hp[k]);
        acc[2*k] += f.x; acc[2*k+1] += f.y;
      }
    }
    float dinv = 1.0f / fmaxf((float)(e - s), 1.0f);
    uint4 hx = hv[n * 4 + q];
    const __half2* hp = (const __half2*)&hx;
#pragma unroll
    for (int k = 0; k < 4; ++k) {
      float2 f = __half22float2(hp[k]);
      xs[ln][q*8 + 2*k]     = f.x;
      xs[ln][q*8 + 2*k + 1] = f.y;
      xs[ln][32 + q*8 + 2*k]     = acc[2*k] * dinv;
      xs[ln][32 + q*8 + 2*k + 1] = acc[2*k+1] * dinv;
    }
  }
  __syncthreads();
  float h2[8];
#pragma unroll
  for (int j = 0; j < 8; ++j) h2[j] = bs[q*8 + j];
  if (act) {
    for (int k = 0; k < 64; ++k) {
      float xk = xs[ln][k];
      const float* wr = Ws + k * 32 + q * 8;
#pragma unroll
      for (int j = 0; j < 8; ++j) h2[j] = fmaf(xk, wr[j], h2[j]);
    }
#pragma unroll
    for (int j = 0; j < 8; ++j) h2[j] = relu_(h2[j]);
  }
  __syncthreads();           // all xs reads done
  if (act) {
#pragma unroll
    for (int j = 0; j < 8; ++j) xs[ln][q*8 + j] = h2[j];
  }
  __syncthreads();
  if (!act) return;
  float au[8], av[8];
#pragma unroll
  for (int j = 0; j < 8; ++j) { au[j] = bes[q*8 + j]; av[j] = 0.f; }
  for (int k = 0; k < 32; ++k) {
    float hk = xs[ln][k];
    const float* wu = Es + k * 32 + q * 8;
    const float* wv = Es + (32 + k) * 32 + q * 8;
#pragma unroll
    for (int j = 0; j < 8; ++j) {
      au[j] = fmaf(hk, wu[j], au[j]);
      av[j] = fmaf(hk, wv[j], av[j]);
    }
  }
  uint4 pu, pv;
  __half2* up = (__half2*)&pu;
  __half2* vp = (__half2*)&pv;
#pragma unroll
  for (int k = 0; k < 4; ++k) {
    up[k] = __floats2half2_rn(au[2*k], au[2*k+1]);
    vp[k] = __floats2half2_rn(av[2*k], av[2*k+1]);
  }
  ((uint4*)u)[n * 4 + q] = pu;
  ((uint4*)v)[n * 4 + q] = pv;
}

// ---- flux in CSR order: per node, u loaded once; v gathered; out scattered
__global__ __launch_bounds__(256) void k_flux_csr(
    const int* __restrict__ rowptr, const int* __restrict__ ecol,
    const int* __restrict__ eorig, const __half* __restrict__ u,
    const __half* __restrict__ v, const float* __restrict__ We2,
    const float* __restrict__ be2, float* __restrict__ out)
{
  int gid = blockIdx.x * 256 + threadIdx.x;
  int n = gid >> 2, q = gid & 3;
  if (n >= NN) return;
  int s = rowptr[n], e = rowptr[n + 1];
  if (s == e) return;
  uint4 ua = ((const uint4*)u)[n * 4 + q];
  const __half2* ah = (const __half2*)&ua;
  float a0x, a0y, a1x, a1y, a2x, a2y, a3x, a3y;
  { float2 f = __half22float2(ah[0]); a0x = f.x; a0y = f.y;
    f = __half22float2(ah[1]); a1x = f.x; a1y = f.y;
    f = __half22float2(ah[2]); a2x = f.x; a2y = f.y;
    f = __half22float2(ah[3]); a3x = f.x; a3y = f.y; }
  const float4* w4 = (const float4*)(We2 + q * 8);
  float4 w0 = w4[0], w1 = w4[1];
  float bias = be2[0];
  const uint4* vv = (const uint4*)v;
  for (int i = s; i < e; ++i) {
    int c = ecol[i];
    uint4 vb = vv[c * 4 + q];
    const __half2* bh = (const __half2*)&vb;
    float2 b0 = __half22float2(bh[0]), b1 = __half22float2(bh[1]);
    float2 b2 = __half22float2(bh[2]), b3 = __half22float2(bh[3]);
    float p = relu_(a0x + b0.x) * w0.x + relu_(a0y + b0.y) * w0.y
            + relu_(a1x + b1.x) * w0.z + relu_(a1y + b1.y) * w0.w
            + relu_(a2x + b2.x) * w1.x + relu_(a2y + b2.y) * w1.y
            + relu_(a3x + b3.x) * w1.z + relu_(a3y + b3.y) * w1.w;
    p += __shfl_xor(p, 1, 4);
    p += __shfl_xor(p, 2, 4);
    if (q == 0) out[eorig[i]] = p + bias;
  }
}

extern "C" void kernel_launch(void* const* d_in, const int* in_sizes, int n_in,
                              void* d_out, int out_size, void* d_ws, size_t ws_size,
                              hipStream_t stream) {
  const float* nf   = (const float*)d_in[0];
  const int*   ei   = (const int*)d_in[1];
  const float* Win  = (const float*)d_in[2];
  const float* bin  = (const float*)d_in[3];
  const float* Wupd = (const float*)d_in[4];
  const float* bupd = (const float*)d_in[5];
  const float* We1  = (const float*)d_in[6];
  const float* be1  = (const float*)d_in[7];
  const float* We2  = (const float*)d_in[8];
  const float* be2  = (const float*)d_in[9];
  float* out = (float*)d_out;

  const int* row = ei;
  const int* col = ei + NE;

  char* ws = (char*)d_ws;
  const size_t HB16 = (size_t)NN * 32 * 2;          // 6.4 MB
  __half* h16a = (__half*)(ws);                     // [0, 6.4)
  uint2*  keys = (uint2*)(ws + HB16);               // [6.4, 26.4) transient
  __half* h16b = (__half*)(ws + HB16);              // aliases keys[0:6.4) after passB
  __half* u    = (__half*)(ws + HB16 + 6400000);    // aliases keys[6.4:12.8)
  __half* v    = (__half*)(ws + HB16 + 12800000);   // aliases keys[12.8:19.2)
  int*    ecol = (int*)(ws + HB16 + 20000000);      // 10 MB
  int*    eorig= (int*)(ws + HB16 + 30000000);      // 10 MB
  char*   tail = ws + HB16 + 40000000;
  int*    rowptr    = (int*)(tail);                 // NN+1
  int*    btot      = (int*)(tail + 400512);
  int*    bbase     = (int*)(tail + 402560);
  int*    blockhist = (int*)(tail + 404608);        // NBUCK*NBLK_A

  const int NB = (NN + 255) / 256;
  const int NBF = (NN + 63) / 64;   // fused kernels: 64 nodes/block

  hipMemsetAsync(btot, 0, NBUCK * 4, stream);
  k_node_embed16<<<NB, 256, 0, stream>>>(nf, Win, bin, h16a);
  k_histA<<<NBLK_A, 512, 0, stream>>>(row, btot, blockhist);
  k_scanA<<<1, 512, 0, stream>>>(btot, bbase);
  k_colscan<<<NBUCK, 512, 0, stream>>>(blockhist, bbase);
  k_partition2<<<NBLK_A, 512, 0, stream>>>(row, col, blockhist, keys);
  k_passB2<<<NBUCK, 512, 0, stream>>>(bbase, keys, ecol, eorig, rowptr);

  k_agg_update<<<NBF, 256, 0, stream>>>(rowptr, ecol, h16a, Wupd, bupd, h16b);
  k_agg_update2_uv<<<NBF, 256, 0, stream>>>(rowptr, ecol, h16b,
                                            Wupd + 2048, bupd + 32,
                                            We1, be1, u, v);
  k_flux_csr<<<(NN * 4 + 255) / 256, 256, 0, stream>>>(rowptr, ecol, eorig,
                                                       u, v, We2, be2, out);
}